// Round 16
// baseline (363.752 us; speedup 1.0000x reference)
//
#include <hip/hip_runtime.h>
#include <stdint.h>

#define B_ 8
#define S_ 4096
#define D_ 192
#define M_ (B_*S_)

typedef short v8s __attribute__((ext_vector_type(8)));
typedef float v4f __attribute__((ext_vector_type(4)));
typedef unsigned short v4us __attribute__((ext_vector_type(4)));

static __device__ __forceinline__ unsigned short f2bf(float f){
  union{float f; unsigned u;} v; v.f=f;
  unsigned u = v.u;
  unsigned r = (u + 0x7fffu + ((u>>16)&1u))>>16;
  return (unsigned short)r;
}
static __device__ __forceinline__ float fexp2(float x){
  return __builtin_amdgcn_exp2f(x);   // v_exp_f32 (native 2^x)
}
static __device__ __forceinline__ unsigned cvtpk(float lo, float hi){
  unsigned r;                          // low16 <- bf16(lo), high16 <- bf16(hi)
  asm("v_cvt_pk_bf16_f32 %0, %1, %2" : "=v"(r) : "v"(lo), "v"(hi));
  return r;
}

typedef const __attribute__((address_space(1))) unsigned int gu32;
typedef __attribute__((address_space(3))) unsigned int lu32;
#define GLL16(gp, lp) __builtin_amdgcn_global_load_lds((gu32*)(gp), (lu32*)(lp), 16, 0, 0)

// ---------------- weight conversion fp32 -> bf16 ----------------
// Wq gets log2(e)/sqrt(D) folded in: softmax runs in exp2 domain.
__global__ void cvt_w_kernel(const float* w0,const float* w1,const float* w2,const float* w3,
                             const float* w4,const float* w5,const float* w6,const float* w7,
                             unsigned short* dst){
  int w = blockIdx.y;
  const float* src;
  switch(w){
    case 0: src=w0; break; case 1: src=w1; break; case 2: src=w2; break; case 3: src=w3; break;
    case 4: src=w4; break; case 5: src=w5; break; case 6: src=w6; break; default: src=w7; break;
  }
  int i = blockIdx.x*256 + threadIdx.x;   // 36864 = 144*256 exact
  float v = src[i];
  if(w==0 || w==4) v *= 0.10411754211316668f;   // log2(e)/sqrt(192)
  dst[(size_t)w*36864 + i] = f2bf(v);
}

// ---------------- fused QKV projection: all 6 (path,which) in one dispatch ----
// grid: 512 blocks. x rows converted once; 6 L2-resident weight matrices looped.
// ALL outputs staged through LDS so global stores are coalesced b128 runs:
//   Q/K: per-wave slab [16][200] shorts, wave-local lgkmcnt (no barrier);
//   V  : block-wide [192][72] transpose stage (Vt[b][d][s] layout out).
#define QSTR 200

__global__ __launch_bounds__(256) void proj_kernel(
    const float* __restrict__ x, const unsigned short* __restrict__ Wb,
    unsigned short* __restrict__ QKV)
{
  __shared__ __align__(16) unsigned short Stage[13824];   // 27.6 KB, aliased
  const size_t MD = (size_t)M_*D_;
  int tid = threadIdx.x;
  int wid = tid>>6, lane = tid&63;
  int lr = lane&15, lg = lane>>4, kb = lg*8;
  int m0 = blockIdx.x*64 + wid*16;
  int row = m0 + lr;

  v8s a[6];
  #pragma unroll
  for(int c=0;c<6;c++){
    const float* xp = &x[(size_t)row*D_ + c*32 + kb];
    float4 f0 = *(const float4*)xp;
    float4 f1 = *(const float4*)(xp+4);
    v8s t;
    t[0]=(short)f2bf(f0.x); t[1]=(short)f2bf(f0.y); t[2]=(short)f2bf(f0.z); t[3]=(short)f2bf(f0.w);
    t[4]=(short)f2bf(f1.x); t[5]=(short)f2bf(f1.y); t[6]=(short)f2bf(f1.z); t[7]=(short)f2bf(f1.w);
    a[c]=t;
  }
  int bidx = m0 / S_;
  int sb   = (blockIdx.x*64) % S_;       // block s-base (4096%64==0 -> bidx uniform)
  int sloc = wid*16 + lg*4;              // local s index for V staging
  unsigned short* slab = Stage + wid*16*QSTR;

  for(int path=0; path<2; path++){
    unsigned short* dstQ = QKV + (size_t)path*3*MD;
    // ---- Q and K: MFMA -> per-wave LDS slab -> coalesced b128 stores ----
    for(int which=0; which<2; which++){
      const unsigned short* W = Wb + (size_t)(path*4 + which)*36864;
      unsigned short* dst = which==0 ? dstQ : dstQ + MD;
      #pragma unroll
      for(int nt=0; nt<12; nt++){
        v4f acc = {0.f,0.f,0.f,0.f};
        int n = nt*16 + lr;
        #pragma unroll
        for(int c=0;c<6;c++){
          v8s bfr = *(const v8s*)&W[(size_t)n*D_ + c*32 + kb];
          acc = __builtin_amdgcn_mfma_f32_16x16x32_bf16(a[c], bfr, acc, 0,0,0);
        }
        int col = nt*16 + lr;
        #pragma unroll
        for(int r=0;r<4;r++) slab[(lg*4+r)*QSTR + col] = f2bf(acc[r]);
      }
      asm volatile("s_waitcnt lgkmcnt(0)" ::: "memory");
      __builtin_amdgcn_sched_barrier(0);
      #pragma unroll
      for(int j=0;j<6;j++){
        int flat = (j*64+lane)*8;          // 0..3064
        int rr = flat/192, cc = flat%192;
        v8s q = *(const v8s*)&slab[rr*QSTR + cc];
        *(v8s*)&dst[(size_t)(m0 - 0 + rr)*D_ + cc] = q;   // rows m0..m0+15
      }
    }
    // ---- V: MFMA -> block-wide transpose stage -> coalesced stores ----
    __syncthreads();                       // all waves done reading slabs (alias)
    {
      const unsigned short* W = Wb + (size_t)(path*4 + 2)*36864;
      #pragma unroll
      for(int nt=0; nt<12; nt++){
        v4f acc = {0.f,0.f,0.f,0.f};
        int n = nt*16 + lr;
        #pragma unroll
        for(int c=0;c<6;c++){
          v8s bfr = *(const v8s*)&W[(size_t)n*D_ + c*32 + kb];
          acc = __builtin_amdgcn_mfma_f32_16x16x32_bf16(a[c], bfr, acc, 0,0,0);
        }
        int col = nt*16 + lr;
        v4us pk;
        pk[0]=f2bf(acc[0]); pk[1]=f2bf(acc[1]); pk[2]=f2bf(acc[2]); pk[3]=f2bf(acc[3]);
        *(v4us*)&Stage[col*72 + sloc] = pk;
      }
      __syncthreads();
      unsigned short* dstV = dstQ + 2*MD;
      size_t vg = (size_t)bidx*D_*S_ + sb;
      #pragma unroll
      for(int j=0;j<6;j++){
        int i = tid + j*256;
        int d = i>>3, s8 = (i&7)*8;
        *(v8s*)&dstV[vg + (size_t)d*S_ + s8] = *(const v8s*)&Stage[d*72 + s8];
      }
      __syncthreads();                     // Stage reused by next path
    }
  }
}

// ---------------- flash attention: DMA dbuf + 1-tile software pipeline ------
// (unchanged from round 15: 217 us, MfmaUtil 43%, conflicts 0)
__global__ __launch_bounds__(256,2) void attn_kernel(unsigned short* __restrict__ QKV)
{
  __shared__ __align__(16) unsigned short Kb[2][32*192];   // 2 x 12288 B
  __shared__ __align__(16) unsigned short Vb[3][192*32];   // 3 x 12288 B (60 KB total)

  int flat = blockIdx.x + 32*blockIdx.y + 256*blockIdx.z;
  int w = (flat&7)*64 + (flat>>3);   // bijective on [0,512)
  int qi = w & 31;
  int b  = (w>>5) & 7;
  int z  = w>>8;

  const size_t MD = (size_t)M_*D_;
  size_t poff = (size_t)z*3*MD;
  const unsigned short* Q  = QKV + poff;
  const unsigned short* K  = QKV + poff + MD;
  const unsigned short* Vt = QKV + poff + 2*MD;
  unsigned short* O = QKV + poff;          // alias Q (block-private rows)

  int q0 = qi*128;
  int tid = threadIdx.x, wid=tid>>6, lane=tid&63;
  int lr = lane&15, lg = lane>>4, kb = lg*8;
  size_t bbase = (size_t)b*S_*D_;
  const size_t vbase = (size_t)b*D_*S_;    // Vt[b][d][s]
  int qrow0 = q0 + wid*32;

  int koff[3], voff[3];
  #pragma unroll
  for(int j=0;j<3;j++){
    int pb = (wid*3+j)*1024 + lane*16;
    int krow = pb/384, kin = pb%384;
    koff[j] = krow*192 + ((kin ^ ((krow&7)<<4))>>1);
    int vrow = pb>>6,  vin = pb&63;
    voff[j] = vrow*4096 + ((vin ^ (((vrow>>1)&3)<<4))>>1);
  }
  int xk = (lr&7)<<4;
  int kco[6];
  #pragma unroll
  for(int c=0;c<6;c++) kco[c] = ((c*64 + lg*16) ^ xk) >> 1;
  int vro = ((lg*16) ^ (((lr>>1)&3)<<4)) >> 1;

  v8s qf[2][6];
  #pragma unroll
  for(int h=0;h<2;h++){
    size_t qrow = bbase + (size_t)(qrow0 + h*16 + lr)*D_;
    #pragma unroll
    for(int c=0;c<6;c++) qf[h][c] = *(const v8s*)&Q[qrow + c*32 + kb];
  }
  float lsum[2] = {0.f, 0.f};
  v4f oacc[2][12];
  #pragma unroll
  for(int h=0;h<2;h++)
    #pragma unroll
    for(int e=0;e<12;e++) oacc[h][e] = (v4f){0.f,0.f,0.f,0.f};

  auto do_qk = [&](int kcur, v4f sacc[2][2]){
    __builtin_amdgcn_s_setprio(1);
    #pragma unroll
    for(int ct=0; ct<2; ct++){
      v4f s0v = {0.f,0.f,0.f,0.f}, s1v = {0.f,0.f,0.f,0.f};
      #pragma unroll
      for(int c=0;c<6;c++){
        v8s kf = *(const v8s*)&Kb[kcur][(ct*16+lr)*192 + kco[c]];
        s0v = __builtin_amdgcn_mfma_f32_16x16x32_bf16(kf, qf[0][c], s0v, 0,0,0);
        s1v = __builtin_amdgcn_mfma_f32_16x16x32_bf16(kf, qf[1][c], s1v, 0,0,0);
      }
      sacc[0][ct]=s0v; sacc[1][ct]=s1v;
    }
    __builtin_amdgcn_s_setprio(0);
  };
  auto do_softmax = [&](v4f sacc[2][2], v8s pa[2]){
    #pragma unroll
    for(int h=0;h<2;h++){
      float p00=fexp2(sacc[h][0][0]), p01=fexp2(sacc[h][0][1]);
      float p02=fexp2(sacc[h][0][2]), p03=fexp2(sacc[h][0][3]);
      float p10=fexp2(sacc[h][1][0]), p11=fexp2(sacc[h][1][1]);
      float p12=fexp2(sacc[h][1][2]), p13=fexp2(sacc[h][1][3]);
      lsum[h] += ((p00+p01)+(p02+p03)) + ((p10+p11)+(p12+p13));
      unsigned X0=cvtpk(p00,p01), X1=cvtpk(p02,p03);
      unsigned Y0=cvtpk(p10,p11), Y1=cvtpk(p12,p13);
      asm("v_permlane32_swap_b32 %0, %1" : "+v"(Y0), "+v"(X0));
      asm("v_permlane32_swap_b32 %0, %1" : "+v"(Y1), "+v"(X1));
      asm("v_permlane16_swap_b32 %0, %1" : "+v"(Y0), "+v"(X0));
      asm("v_permlane16_swap_b32 %0, %1" : "+v"(Y1), "+v"(X1));
      union{ v8s s; unsigned w[4]; } u;
      u.w[0] = X0;  u.w[1] = X1;  u.w[2] = Y0;  u.w[3] = Y1;
      pa[h] = u.s;
    }
  };
  auto do_pv = [&](int vcur, v8s pa[2]){
    __builtin_amdgcn_s_setprio(1);
    #pragma unroll
    for(int e=0;e<12;e++){
      v8s vbf = *(const v8s*)&Vb[vcur][(e*16+lr)*32 + vro];
      oacc[0][e] = __builtin_amdgcn_mfma_f32_16x16x32_bf16(pa[0], vbf, oacc[0][e], 0,0,0);
      oacc[1][e] = __builtin_amdgcn_mfma_f32_16x16x32_bf16(pa[1], vbf, oacc[1][e], 0,0,0);
    }
    __builtin_amdgcn_s_setprio(0);
  };

  #pragma unroll
  for(int j=0;j<3;j++){
    GLL16(K  + bbase + koff[j], &Kb[0][(wid*3+j)*512]);
    GLL16(Vt + vbase + voff[j], &Vb[0][(wid*3+j)*512]);
  }
  asm volatile("s_waitcnt vmcnt(0)" ::: "memory");
  __syncthreads();

  v8s pa_prev[2];
  {
    v4f sacc[2][2];
    do_qk(0, sacc);
    const unsigned short* kg = K  + bbase + (size_t)6144;
    const unsigned short* vg = Vt + vbase + (size_t)32;
    #pragma unroll
    for(int j=0;j<3;j++){
      GLL16(kg + koff[j], &Kb[1][(wid*3+j)*512]);
      GLL16(vg + voff[j], &Vb[1][(wid*3+j)*512]);
    }
    __builtin_amdgcn_sched_barrier(0);
    do_softmax(sacc, pa_prev);
  }

  for(int t=1; t<128; t++){
    asm volatile("s_waitcnt vmcnt(0)" ::: "memory");
    __syncthreads();
    int kcur = t&1;
    int vprev = (t-1)%3, vnext = (t+1)%3;

    v4f sacc[2][2];
    do_qk(kcur, sacc);

    if(t<127){
      const unsigned short* kg = K  + bbase + (size_t)(t+1)*6144;
      const unsigned short* vg = Vt + vbase + (size_t)(t+1)*32;
      #pragma unroll
      for(int j=0;j<3;j++){
        GLL16(kg + koff[j], &Kb[(t+1)&1][(wid*3+j)*512]);
        GLL16(vg + voff[j], &Vb[vnext][(wid*3+j)*512]);
      }
    }
    __builtin_amdgcn_sched_barrier(0);

    do_pv(vprev, pa_prev);
    do_softmax(sacc, pa_prev);
  }
  do_pv(127%3, pa_prev);

  float invr[2][4];
  #pragma unroll
  for(int h=0;h<2;h++){
    float ps = lsum[h];
    ps += __shfl_xor(ps, 16);
    ps += __shfl_xor(ps, 32);
    float iv = 1.0f/ps;
    #pragma unroll
    for(int r=0;r<4;r++) invr[h][r] = __shfl(iv, lg*4+r, 16);
  }
  #pragma unroll
  for(int h=0;h<2;h++){
    size_t orow0 = bbase + (size_t)(qrow0 + h*16 + lg*4)*D_;
    #pragma unroll
    for(int e=0;e<12;e++){
      #pragma unroll
      for(int r=0;r<4;r++){
        O[orow0 + (size_t)r*D_ + e*16 + lr] = f2bf(oacc[h][e][r]*invr[h][r]);
      }
    }
  }
}

// ---------------- final: R = O @ Wo^T (both), combine, column fixes ----------
// Output staged through per-wave LDS slab (fp32, stride 196) -> coalesced
// global_store_dwordx4 (was 48 scalar fp32 stores per thread).
#define OSTR 196

__global__ __launch_bounds__(256) void final_kernel(
  const float* __restrict__ x,
  const unsigned short* __restrict__ Or,
  const unsigned short* __restrict__ Ow,
  const unsigned short* __restrict__ WoR,
  const unsigned short* __restrict__ WoW,
  float* __restrict__ out)
{
  __shared__ __align__(16) float Ostage[64*OSTR];   // 50.2 KB
  int tid=threadIdx.x, wid=tid>>6, lane=tid&63;
  int lr=lane&15, lg=lane>>4, kb=lg*8;
  int m0 = blockIdx.x*64 + wid*16;
  int arow = m0 + lr;
  float* slab = Ostage + wid*16*OSTR;
  v8s ar[6], aw[6];
  #pragma unroll
  for(int c=0;c<6;c++){
    ar[c] = *(const v8s*)&Or[(size_t)arow*D_ + c*32 + kb];
    aw[c] = *(const v8s*)&Ow[(size_t)arow*D_ + c*32 + kb];
  }
  int bidx = m0 / S_;
  float rf = x[(size_t)bidx*S_*D_ + 156];
  float wf = x[(size_t)bidx*S_*D_ + 157];
  #pragma unroll
  for(int nt=0; nt<12; nt++){
    v4f accR={0.f,0.f,0.f,0.f}, accW={0.f,0.f,0.f,0.f};
    int n = nt*16 + lr;
    #pragma unroll
    for(int c=0;c<6;c++){
      v8s br = *(const v8s*)&WoR[(size_t)n*D_ + c*32 + kb];
      accR = __builtin_amdgcn_mfma_f32_16x16x32_bf16(ar[c], br, accR,0,0,0);
      v8s bw = *(const v8s*)&WoW[(size_t)n*D_ + c*32 + kb];
      accW = __builtin_amdgcn_mfma_f32_16x16x32_bf16(aw[c], bw, accW,0,0,0);
    }
    #pragma unroll
    for(int r=0;r<4;r++){
      int row = m0 + lg*4 + r;
      int col = nt*16 + lr;
      float xv = x[(size_t)row*D_ + col];
      float val = xv + rf*(accR[r]-xv) + wf*(accW[r]-xv);
      if(col==156||col==157) val = 0.f;
      else if(col==158) val = rf+wf;
      slab[(lg*4+r)*OSTR + col] = val;
    }
  }
  asm volatile("s_waitcnt lgkmcnt(0)" ::: "memory");
  __builtin_amdgcn_sched_barrier(0);
  #pragma unroll
  for(int j=0;j<12;j++){
    int flat = (j*64+lane)*4;            // 0..3068
    int rr = flat/192, cc = flat%192;
    float4 o = *(const float4*)&slab[rr*OSTR + cc];
    *(float4*)&out[(size_t)(m0+rr)*D_ + cc] = o;
  }
}

extern "C" void kernel_launch(void* const* d_in, const int* in_sizes, int n_in,
                              void* d_out, int out_size, void* d_ws, size_t ws_size,
                              hipStream_t stream) {
  const float* x = (const float*)d_in[0];
  unsigned short* ws = (unsigned short*)d_ws;
  const size_t WSZ = 36864;           // 192*192
  const size_t MD  = (size_t)M_*D_;   // 32768*192
  unsigned short* Wb  = ws;           // 8 * WSZ
  unsigned short* QKV = ws + 8*WSZ;   // [2 paths][{Q,K,Vt}][MD]; O aliases Q

  cvt_w_kernel<<<dim3(144,8),256,0,stream>>>(
      (const float*)d_in[1],(const float*)d_in[2],(const float*)d_in[3],(const float*)d_in[4],
      (const float*)d_in[5],(const float*)d_in[6],(const float*)d_in[7],(const float*)d_in[8], Wb);

  proj_kernel<<<512,256,0,stream>>>(x, Wb, QKV);
  attn_kernel<<<dim3(32,8,2),256,0,stream>>>(QKV);
  final_kernel<<<512,256,0,stream>>>(x, QKV /*Or=Qr*/, QKV+3*MD /*Ow=Qw*/,
                                     Wb+3*WSZ, Wb+7*WSZ, (float*)d_out);
}

// Round 17
// 356.802 us; speedup vs baseline: 1.0195x; 1.0195x over previous
//
#include <hip/hip_runtime.h>
#include <stdint.h>

#define B_ 8
#define S_ 4096
#define D_ 192
#define M_ (B_*S_)

typedef short v8s __attribute__((ext_vector_type(8)));
typedef float v4f __attribute__((ext_vector_type(4)));
typedef unsigned short v4us __attribute__((ext_vector_type(4)));

static __device__ __forceinline__ unsigned short f2bf(float f){
  union{float f; unsigned u;} v; v.f=f;
  unsigned u = v.u;
  unsigned r = (u + 0x7fffu + ((u>>16)&1u))>>16;
  return (unsigned short)r;
}
static __device__ __forceinline__ float fexp2(float x){
  return __builtin_amdgcn_exp2f(x);   // v_exp_f32 (native 2^x)
}
static __device__ __forceinline__ unsigned cvtpk(float lo, float hi){
  unsigned r;                          // low16 <- bf16(lo), high16 <- bf16(hi)
  asm("v_cvt_pk_bf16_f32 %0, %1, %2" : "=v"(r) : "v"(lo), "v"(hi));
  return r;
}

typedef const __attribute__((address_space(1))) unsigned int gu32;
typedef __attribute__((address_space(3))) unsigned int lu32;
#define GLL16(gp, lp) __builtin_amdgcn_global_load_lds((gu32*)(gp), (lu32*)(lp), 16, 0, 0)

// ---------------- weight conversion fp32 -> bf16 ----------------
// Wq gets log2(e)/sqrt(D) folded in: softmax runs in exp2 domain.
__global__ void cvt_w_kernel(const float* w0,const float* w1,const float* w2,const float* w3,
                             const float* w4,const float* w5,const float* w6,const float* w7,
                             unsigned short* dst){
  int w = blockIdx.y;
  const float* src;
  switch(w){
    case 0: src=w0; break; case 1: src=w1; break; case 2: src=w2; break; case 3: src=w3; break;
    case 4: src=w4; break; case 5: src=w5; break; case 6: src=w6; break; default: src=w7; break;
  }
  int i = blockIdx.x*256 + threadIdx.x;   // 36864 = 144*256 exact
  float v = src[i];
  if(w==0 || w==4) v *= 0.10411754211316668f;   // log2(e)/sqrt(192)
  dst[(size_t)w*36864 + i] = f2bf(v);
}

// ---------------- fused QKV projection (round-15 form) ----------------
// grid: 512 blocks. x rows converted once; 6 L2-resident weight matrices looped.
// Q/K direct stores; V transposed through LDS stage -> coalesced stores.
__global__ __launch_bounds__(256) void proj_kernel(
    const float* __restrict__ x, const unsigned short* __restrict__ Wb,
    unsigned short* __restrict__ QKV)
{
  __shared__ __align__(16) unsigned short Vstage[192*72];   // 27.6 KB
  const size_t MD = (size_t)M_*D_;
  int tid = threadIdx.x;
  int wid = tid>>6, lane = tid&63;
  int lr = lane&15, lg = lane>>4, kb = lg*8;
  int m0 = blockIdx.x*64 + wid*16;
  int row = m0 + lr;

  v8s a[6];
  #pragma unroll
  for(int c=0;c<6;c++){
    const float* xp = &x[(size_t)row*D_ + c*32 + kb];
    float4 f0 = *(const float4*)xp;
    float4 f1 = *(const float4*)(xp+4);
    v8s t;
    t[0]=(short)f2bf(f0.x); t[1]=(short)f2bf(f0.y); t[2]=(short)f2bf(f0.z); t[3]=(short)f2bf(f0.w);
    t[4]=(short)f2bf(f1.x); t[5]=(short)f2bf(f1.y); t[6]=(short)f2bf(f1.z); t[7]=(short)f2bf(f1.w);
    a[c]=t;
  }
  int bidx = m0 / S_;
  int sb   = (blockIdx.x*64) % S_;       // block s-base (4096%64==0 -> bidx uniform)
  int sloc = wid*16 + lg*4;              // local s index for V staging

  for(int path=0; path<2; path++){
    unsigned short* dstQ = QKV + (size_t)path*3*MD;
    for(int which=0; which<2; which++){
      const unsigned short* W = Wb + (size_t)(path*4 + which)*36864;
      unsigned short* dst = which==0 ? dstQ : dstQ + MD;
      #pragma unroll
      for(int nt=0; nt<12; nt++){
        v4f acc = {0.f,0.f,0.f,0.f};
        int n = nt*16 + lr;
        #pragma unroll
        for(int c=0;c<6;c++){
          v8s bfr = *(const v8s*)&W[(size_t)n*D_ + c*32 + kb];
          acc = __builtin_amdgcn_mfma_f32_16x16x32_bf16(a[c], bfr, acc, 0,0,0);
        }
        int col = nt*16 + lr;
        int r0 = m0 + lg*4;
        #pragma unroll
        for(int r=0;r<4;r++) dst[(size_t)(r0+r)*D_ + col] = f2bf(acc[r]);
      }
    }
    // V: MFMA -> LDS transpose stage -> coalesced stores
    {
      const unsigned short* W = Wb + (size_t)(path*4 + 2)*36864;
      #pragma unroll
      for(int nt=0; nt<12; nt++){
        v4f acc = {0.f,0.f,0.f,0.f};
        int n = nt*16 + lr;
        #pragma unroll
        for(int c=0;c<6;c++){
          v8s bfr = *(const v8s*)&W[(size_t)n*D_ + c*32 + kb];
          acc = __builtin_amdgcn_mfma_f32_16x16x32_bf16(a[c], bfr, acc, 0,0,0);
        }
        int col = nt*16 + lr;
        v4us pk;
        pk[0]=f2bf(acc[0]); pk[1]=f2bf(acc[1]); pk[2]=f2bf(acc[2]); pk[3]=f2bf(acc[3]);
        *(v4us*)&Vstage[col*72 + sloc] = pk;
      }
      __syncthreads();
      unsigned short* dstV = dstQ + 2*MD;
      size_t vg = (size_t)bidx*D_*S_ + sb;
      #pragma unroll
      for(int j=0;j<6;j++){
        int i = tid + j*256;
        int d = i>>3, s8 = (i&7)*8;
        *(v8s*)&dstV[vg + (size_t)d*S_ + s8] = *(const v8s*)&Vstage[d*72 + s8];
      }
      __syncthreads();   // Vstage reused by next path
    }
  }
}

// ---------------- flash attention: 8 waves x 16 q-rows (occupancy 2x) -------
// grid 512 blocks XCD-remapped, block = 512 threads. KV tile 32, K dbuf, V 3buf.
// Waves 0-3 stage K, waves 4-7 stage V (3 DMA/thread/tile). Same 1-tile
// pipeline: QK(t) -> DMA(t+1) -> PV(t-1) -> softmax(t). In-register P via
// swapped QK^T + cvt_pk + permlane swaps. Static softmax (m==0 exact).
// Per-thread state ~110 VGPR -> target 4 waves/SIMD (vs 2 before).
__global__ __launch_bounds__(512,3) void attn_kernel(unsigned short* __restrict__ QKV)
{
  __shared__ __align__(16) unsigned short Kb[2][32*192];   // 2 x 12288 B
  __shared__ __align__(16) unsigned short Vb[3][192*32];   // 3 x 12288 B (60 KB)

  int flat = blockIdx.x + 32*blockIdx.y + 256*blockIdx.z;
  int w = (flat&7)*64 + (flat>>3);   // bijective on [0,512)
  int qi = w & 31;
  int b  = (w>>5) & 7;
  int z  = w>>8;

  const size_t MD = (size_t)M_*D_;
  size_t poff = (size_t)z*3*MD;
  const unsigned short* Q  = QKV + poff;
  const unsigned short* K  = QKV + poff + MD;
  const unsigned short* Vt = QKV + poff + 2*MD;
  unsigned short* O = QKV + poff;          // alias Q (block-private rows)

  int q0 = qi*128;
  int tid = threadIdx.x, wid=tid>>6, lane=tid&63;
  int lr = lane&15, lg = lane>>4, kb = lg*8;
  size_t bbase = (size_t)b*S_*D_;
  const size_t vbase = (size_t)b*D_*S_;    // Vt[b][d][s]
  int qrow0 = q0 + wid*16;

  // staging: waves 0-3 own K chunks, waves 4-7 own V chunks (12 x 1KB each)
  bool isK = wid < 4;
  int cb = (isK ? wid : wid-4)*3;
  int soff[3];
  #pragma unroll
  for(int j=0;j<3;j++){
    int pb = (cb+j)*1024 + lane*16;        // byte position in tile
    if(isK){
      int krow = pb/384, kin = pb%384;
      soff[j] = krow*192 + ((kin ^ ((krow&7)<<4))>>1);
    } else {
      int vrow = pb>>6,  vin = pb&63;
      soff[j] = vrow*4096 + ((vin ^ (((vrow>>1)&3)<<4))>>1);
    }
  }
  // swizzled read offsets (shorts)
  int xk = (lr&7)<<4;
  int kco[6];
  #pragma unroll
  for(int c=0;c<6;c++) kco[c] = ((c*64 + lg*16) ^ xk) >> 1;
  int vro = ((lg*16) ^ (((lr>>1)&3)<<4)) >> 1;

  v8s qf[6];
  {
    size_t qrow = bbase + (size_t)(qrow0 + lr)*D_;
    #pragma unroll
    for(int c=0;c<6;c++) qf[c] = *(const v8s*)&Q[qrow + c*32 + kb];
  }
  float lsum = 0.f;
  v4f oacc[12];
  #pragma unroll
  for(int e=0;e<12;e++) oacc[e] = (v4f){0.f,0.f,0.f,0.f};

  auto stage = [&](int t, int kbuf, int vbuf){
    if(isK){
      const unsigned short* kg = K + bbase + (size_t)t*6144;
      #pragma unroll
      for(int j=0;j<3;j++) GLL16(kg + soff[j], &Kb[kbuf][(cb+j)*512]);
    } else {
      const unsigned short* vg = Vt + vbase + (size_t)t*32;
      #pragma unroll
      for(int j=0;j<3;j++) GLL16(vg + soff[j], &Vb[vbuf][(cb+j)*512]);
    }
  };
  auto do_qk = [&](int kcur, v4f sacc[2]){
    __builtin_amdgcn_s_setprio(1);
    #pragma unroll
    for(int ct=0; ct<2; ct++){
      v4f s = {0.f,0.f,0.f,0.f};
      #pragma unroll
      for(int c=0;c<6;c++){
        v8s kf = *(const v8s*)&Kb[kcur][(ct*16+lr)*192 + kco[c]];
        s = __builtin_amdgcn_mfma_f32_16x16x32_bf16(kf, qf[c], s, 0,0,0);
      }
      sacc[ct]=s;
    }
    __builtin_amdgcn_s_setprio(0);
  };
  auto do_softmax = [&](v4f sacc[2], v8s& pa){
    float p00=fexp2(sacc[0][0]), p01=fexp2(sacc[0][1]);
    float p02=fexp2(sacc[0][2]), p03=fexp2(sacc[0][3]);
    float p10=fexp2(sacc[1][0]), p11=fexp2(sacc[1][1]);
    float p12=fexp2(sacc[1][2]), p13=fexp2(sacc[1][3]);
    lsum += ((p00+p01)+(p02+p03)) + ((p10+p11)+(p12+p13));
    unsigned X0=cvtpk(p00,p01), X1=cvtpk(p02,p03);
    unsigned Y0=cvtpk(p10,p11), Y1=cvtpk(p12,p13);
    asm("v_permlane32_swap_b32 %0, %1" : "+v"(Y0), "+v"(X0));
    asm("v_permlane32_swap_b32 %0, %1" : "+v"(Y1), "+v"(X1));
    asm("v_permlane16_swap_b32 %0, %1" : "+v"(Y0), "+v"(X0));
    asm("v_permlane16_swap_b32 %0, %1" : "+v"(Y1), "+v"(X1));
    union{ v8s s; unsigned w[4]; } u;
    u.w[0] = X0;  u.w[1] = X1;  u.w[2] = Y0;  u.w[3] = Y1;
    pa = u.s;
  };
  auto do_pv = [&](int vcur, v8s pa){
    __builtin_amdgcn_s_setprio(1);
    #pragma unroll
    for(int e=0;e<12;e++){
      v8s vbf = *(const v8s*)&Vb[vcur][(e*16+lr)*32 + vro];
      oacc[e] = __builtin_amdgcn_mfma_f32_16x16x32_bf16(pa, vbf, oacc[e], 0,0,0);
    }
    __builtin_amdgcn_s_setprio(0);
  };

  // prologue: tile 0 into K0/V0
  stage(0, 0, 0);
  asm volatile("s_waitcnt vmcnt(0)" ::: "memory");
  __syncthreads();

  v8s pa_prev;
  {
    v4f sacc[2];
    do_qk(0, sacc);
    stage(1, 1, 1);
    __builtin_amdgcn_sched_barrier(0);
    do_softmax(sacc, pa_prev);
  }

  for(int t=1; t<128; t++){
    asm volatile("s_waitcnt vmcnt(0)" ::: "memory");
    __syncthreads();                       // tile t staged everywhere
    v4f sacc[2];
    do_qk(t&1, sacc);
    if(t<127) stage(t+1, (t+1)&1, (t+1)%3);
    __builtin_amdgcn_sched_barrier(0);
    do_pv((t-1)%3, pa_prev);               // PV(t-1) independent of QK(t)
    do_softmax(sacc, pa_prev);             // softmax(t) overlaps PV drain
  }
  do_pv(127%3, pa_prev);

  // epilogue: per-lane partial sums -> row inverses -> O write
  float ps = lsum;
  ps += __shfl_xor(ps, 16);
  ps += __shfl_xor(ps, 32);
  float iv = 1.0f/ps;                      // inv for q-row = lr
  float invr[4];
  #pragma unroll
  for(int r=0;r<4;r++) invr[r] = __shfl(iv, lg*4+r, 16);
  size_t orow0 = bbase + (size_t)(qrow0 + lg*4)*D_;
  #pragma unroll
  for(int e=0;e<12;e++){
    #pragma unroll
    for(int r=0;r<4;r++){
      O[orow0 + (size_t)r*D_ + e*16 + lr] = f2bf(oacc[e][r]*invr[r]);
    }
  }
}

// ---------------- final (round-15 form): R = O @ Wo^T, combine, fixes -------
__global__ __launch_bounds__(256) void final_kernel(
  const float* __restrict__ x,
  const unsigned short* __restrict__ Or,
  const unsigned short* __restrict__ Ow,
  const unsigned short* __restrict__ WoR,
  const unsigned short* __restrict__ WoW,
  float* __restrict__ out)
{
  int tid=threadIdx.x, wid=tid>>6, lane=tid&63;
  int lr=lane&15, lg=lane>>4, kb=lg*8;
  int m0 = blockIdx.x*64 + wid*16;
  int arow = m0 + lr;
  v8s ar[6], aw[6];
  #pragma unroll
  for(int c=0;c<6;c++){
    ar[c] = *(const v8s*)&Or[(size_t)arow*D_ + c*32 + kb];
    aw[c] = *(const v8s*)&Ow[(size_t)arow*D_ + c*32 + kb];
  }
  int bidx = m0 / S_;
  float rf = x[(size_t)bidx*S_*D_ + 156];
  float wf = x[(size_t)bidx*S_*D_ + 157];
  #pragma unroll
  for(int nt=0; nt<12; nt++){
    v4f accR={0.f,0.f,0.f,0.f}, accW={0.f,0.f,0.f,0.f};
    int n = nt*16 + lr;
    #pragma unroll
    for(int c=0;c<6;c++){
      v8s br = *(const v8s*)&WoR[(size_t)n*D_ + c*32 + kb];
      accR = __builtin_amdgcn_mfma_f32_16x16x32_bf16(ar[c], br, accR,0,0,0);
      v8s bw = *(const v8s*)&WoW[(size_t)n*D_ + c*32 + kb];
      accW = __builtin_amdgcn_mfma_f32_16x16x32_bf16(aw[c], bw, accW,0,0,0);
    }
    #pragma unroll
    for(int r=0;r<4;r++){
      int row = m0 + lg*4 + r;
      int col = nt*16 + lr;
      float xv = x[(size_t)row*D_ + col];
      float val = xv + rf*(accR[r]-xv) + wf*(accW[r]-xv);
      if(col==156||col==157) val = 0.f;
      else if(col==158) val = rf+wf;
      out[(size_t)row*D_ + col] = val;
    }
  }
}

extern "C" void kernel_launch(void* const* d_in, const int* in_sizes, int n_in,
                              void* d_out, int out_size, void* d_ws, size_t ws_size,
                              hipStream_t stream) {
  const float* x = (const float*)d_in[0];
  unsigned short* ws = (unsigned short*)d_ws;
  const size_t WSZ = 36864;           // 192*192
  const size_t MD  = (size_t)M_*D_;   // 32768*192
  unsigned short* Wb  = ws;           // 8 * WSZ
  unsigned short* QKV = ws + 8*WSZ;   // [2 paths][{Q,K,Vt}][MD]; O aliases Q

  cvt_w_kernel<<<dim3(144,8),256,0,stream>>>(
      (const float*)d_in[1],(const float*)d_in[2],(const float*)d_in[3],(const float*)d_in[4],
      (const float*)d_in[5],(const float*)d_in[6],(const float*)d_in[7],(const float*)d_in[8], Wb);

  proj_kernel<<<512,256,0,stream>>>(x, Wb, QKV);
  attn_kernel<<<dim3(32,8,2),512,0,stream>>>(QKV);
  final_kernel<<<512,256,0,stream>>>(x, QKV /*Or=Qr*/, QKV+3*MD /*Ow=Qw*/,
                                     Wb+3*WSZ, Wb+7*WSZ, (float*)d_out);
}